// Round 1
// baseline (578.971 us; speedup 1.0000x reference)
//
#include <hip/hip_runtime.h>
#include <stdint.h>

// NVFP4 Linear fwd: y = dq(rht(x)) @ dq(rht(w))^T + bias
// Plan: quantize x,w -> bf16 (exact: level*e4m3scale fits in 6 significand bits),
// then 128x128-tile bf16 MFMA GEMM (m97 structure + LDS XOR swizzle).

typedef __bf16 bf16x8 __attribute__((ext_vector_type(8)));
typedef float f32x4 __attribute__((ext_vector_type(4)));

// ---------------- quantization kernel ----------------

// RNE round of x (>=0) onto the e4m3fn grid (handles subnormals; no saturation
// needed: amax/6 << 448 for this problem).
__device__ __forceinline__ float e4m3_rt(float x) {
    unsigned int u = __float_as_uint(x);
    int ex = (int)((u >> 23) & 0xffu) - 127;
    if (ex < -6) ex = -6;                       // subnormal region: step 2^-9
    float qs = __uint_as_float((unsigned)(127 + 3 - ex) << 23);  // 2^(3-ex)
    float qi = __uint_as_float((unsigned)(127 + ex - 3) << 23);  // 2^(ex-3)
    return rintf(x * qs) * qi;                  // exact pow2 scaling, RNE ties-even
}

__global__ __launch_bounds__(256) void quant_rht_kernel(
    const float* __restrict__ X, const float* __restrict__ signs,
    uint16_t* __restrict__ Q, int ngroups)
{
    int gid = blockIdx.x * 256 + threadIdx.x;
    if (gid >= ngroups) return;

    const float4* p = (const float4*)(X + (size_t)gid * 16);
    float4 v0 = p[0], v1 = p[1], v2 = p[2], v3 = p[3];
    float t[16] = { v0.x, v0.y, v0.z, v0.w, v1.x, v1.y, v1.z, v1.w,
                    v2.x, v2.y, v2.z, v2.w, v3.x, v3.y, v3.z, v3.w };
#pragma unroll
    for (int i = 0; i < 16; i++) t[i] *= signs[i];

    // FWHT-16 (Sylvester order == block-doubled H), then *0.25 (orthonormal).
#pragma unroll
    for (int len = 1; len < 16; len <<= 1) {
#pragma unroll
        for (int i = 0; i < 16; i += 2 * len) {
#pragma unroll
            for (int j = 0; j < len; j++) {
                float a = t[i + j], b = t[i + j + len];
                t[i + j] = a + b;
                t[i + j + len] = a - b;
            }
        }
    }
    float amax = 0.0f;
#pragma unroll
    for (int i = 0; i < 16; i++) { t[i] *= 0.25f; amax = fmaxf(amax, fabsf(t[i])); }

    float scale = e4m3_rt(amax / 6.0f);
    float safe = (scale == 0.0f) ? 1.0f : scale;

    unsigned int w[8];
#pragma unroll
    for (int i = 0; i < 8; i++) {
        float d01[2];
#pragma unroll
        for (int h = 0; h < 2; h++) {
            float tv = t[2 * i + h];
            float aa = fminf(fabsf(tv) / safe, 6.0f);
            // searchsorted(mids, aa, 'left'): ties round DOWN -> strict >
            float q = aa > 2.5f ? (aa > 5.0f ? 6.0f : (aa > 3.5f ? 4.0f : 3.0f))
                                : (aa > 1.25f ? (aa > 1.75f ? 2.0f : 1.5f)
                                              : (aa > 0.75f ? 1.0f
                                                 : (aa > 0.25f ? 0.5f : 0.0f)));
            d01[h] = copysignf(q * scale, tv);   // exact in bf16
        }
        // exact bf16: low 16 bits of f32 are zero -> truncate
        w[i] = (__float_as_uint(d01[0]) >> 16) |
               (__float_as_uint(d01[1]) & 0xFFFF0000u);
    }
    uint4* q4 = (uint4*)(Q + (size_t)gid * 16);
    q4[0] = make_uint4(w[0], w[1], w[2], w[3]);
    q4[1] = make_uint4(w[4], w[5], w[6], w[7]);
}

// ---------------- GEMM: C[M,N] = A[M,K] * B[N,K]^T + bias[N] ----------------

#define TM 128
#define TN 128
#define BK 64

__global__ __launch_bounds__(256) void gemm_bt_bias(
    const uint16_t* __restrict__ A,   // bf16 bits, [M,K]
    const uint16_t* __restrict__ B,   // bf16 bits, [N,K]
    const float* __restrict__ bias,   // [N]
    float* __restrict__ C,            // [M,N]
    int M, int N, int K)
{
    // LDS tiles as 16B chunks. Chunk index for (row r, kgroup kg):
    //   c = r*8 + (kg ^ (r&7))   (XOR swizzle -> ds_read_b128 spreads banks)
    __shared__ uint4 As[TM * BK / 8];   // 1024 chunks = 16 KiB
    __shared__ uint4 Bs[TN * BK / 8];

    const int tid  = threadIdx.x;
    const int bm   = blockIdx.y, bn = blockIdx.x;
    const int wave = tid >> 6,  lane = tid & 63;
    const int wm   = wave >> 1, wn = wave & 1;     // 2x2 waves of 64x64
    const int lm   = lane & 15, g4 = lane >> 4;

    // Staging: thread t owns LDS chunk (issue*256 + t); inverse-swizzled global:
    //   r = i*32 + (t>>3), kg = (t&7) ^ ((t>>3)&7)  (kg issue-invariant)
    const int sr = tid >> 3;
    const int kg = (tid & 7) ^ (sr & 7);
    const uint16_t* ag = A + (size_t)(bm * TM + sr) * (size_t)K + kg * 8;
    const uint16_t* bg = B + (size_t)(bn * TN + sr) * (size_t)K + kg * 8;
    char* asd = (char*)&As[0] + tid * 16;
    char* bsd = (char*)&Bs[0] + tid * 16;

    f32x4 acc[4][4];
#pragma unroll
    for (int i = 0; i < 4; i++)
#pragma unroll
        for (int j = 0; j < 4; j++) acc[i][j] = (f32x4){0.f, 0.f, 0.f, 0.f};

    for (int kt = 0; kt < K; kt += BK) {
        __syncthreads();   // prev compute done before overwrite
#pragma unroll
        for (int i = 0; i < 4; i++) {
            __builtin_amdgcn_global_load_lds(
                (const __attribute__((address_space(1))) unsigned int*)(ag + (size_t)i * 32 * K),
                (__attribute__((address_space(3))) unsigned int*)(asd + i * 4096),
                16, 0, 0);
            __builtin_amdgcn_global_load_lds(
                (const __attribute__((address_space(1))) unsigned int*)(bg + (size_t)i * 32 * K),
                (__attribute__((address_space(3))) unsigned int*)(bsd + i * 4096),
                16, 0, 0);
        }
        ag += BK; bg += BK;
        __syncthreads();   // compiler drains vmcnt before barrier

#pragma unroll
        for (int ks = 0; ks < 2; ks++) {
            bf16x8 af[4], bf[4];
#pragma unroll
            for (int i = 0; i < 4; i++) {
                int rA = wm * 64 + i * 16 + lm;         // rA&7 == lm&7
                af[i] = __builtin_bit_cast(bf16x8, As[rA * 8 + ((ks * 4 + g4) ^ (lm & 7))]);
                int rB = wn * 64 + i * 16 + lm;
                bf[i] = __builtin_bit_cast(bf16x8, Bs[rB * 8 + ((ks * 4 + g4) ^ (lm & 7))]);
            }
#pragma unroll
            for (int i = 0; i < 4; i++)
#pragma unroll
                for (int j = 0; j < 4; j++)
                    acc[i][j] = __builtin_amdgcn_mfma_f32_16x16x32_bf16(
                        af[i], bf[j], acc[i][j], 0, 0, 0);
        }
    }

    // Epilogue. C/D layout: col = lane&15, row = (lane>>4)*4 + reg  [m89/m91]
#pragma unroll
    for (int j = 0; j < 4; j++) {
        int col = bn * TN + wn * 64 + j * 16 + lm;
        float bj = bias[col];
#pragma unroll
        for (int i = 0; i < 4; i++) {
            int row0 = bm * TM + wm * 64 + i * 16 + g4 * 4;
#pragma unroll
            for (int r = 0; r < 4; r++) {
                C[(size_t)(row0 + r) * (size_t)N + col] = acc[i][j][r] + bj;
            }
        }
    }
}

// ---------------- launch ----------------

extern "C" void kernel_launch(void* const* d_in, const int* in_sizes, int n_in,
                              void* d_out, int out_size, void* d_ws, size_t ws_size,
                              hipStream_t stream)
{
    const float* x        = (const float*)d_in[0];
    const float* w        = (const float*)d_in[1];
    const float* bias     = (const float*)d_in[2];
    const float* signs_in = (const float*)d_in[3];
    // d_in[4] = signs_grad: unused in forward

    const int OUT = in_sizes[2];              // 4096
    const int IN  = in_sizes[1] / OUT;        // 4096
    const int M   = in_sizes[0] / IN;         // 8192

    uint16_t* xq = (uint16_t*)d_ws;                    // [M, IN] bf16
    uint16_t* wq = xq + (size_t)M * (size_t)IN;        // [OUT, IN] bf16
    (void)ws_size; (void)n_in; (void)out_size;

    int ngx = (int)((size_t)M * IN / 16);
    int ngw = (int)((size_t)OUT * IN / 16);
    quant_rht_kernel<<<(ngx + 255) / 256, 256, 0, stream>>>(x, signs_in, xq, ngx);
    quant_rht_kernel<<<(ngw + 255) / 256, 256, 0, stream>>>(w, signs_in, wq, ngw);

    dim3 grid(OUT / TN, M / TM);
    gemm_bt_bias<<<grid, 256, 0, stream>>>(xq, wq, bias, (float*)d_out, M, OUT, IN);
}